// Round 5
// baseline (180.018 us; speedup 1.0000x reference)
//
#include <hip/hip_runtime.h>
#include <math.h>

#define FDIM 512
#define NL 1600
#define NR 64
#define NM (NL + NR)   // 1664 gathered rows
#define NBLK 256
#define NTHR 1024

typedef __attribute__((ext_vector_type(8))) short short8;      // 8 bf16 = 4 VGPR (MFMA A/B frag)
typedef __attribute__((ext_vector_type(4))) float f32x4;       // MFMA C/D frag
typedef __attribute__((ext_vector_type(8))) unsigned short ushort8;
typedef __attribute__((ext_vector_type(4))) unsigned short ushort4v;

// Self-resetting grid barrier state. Zero-initialized at module load.
// g_gen is monotonic (only equality-tested -> works for any start value across
// replays); g_cnt is returned to 0 by the last arriver of every barrier.
__device__ unsigned g_cnt = 0;
__device__ unsigned g_gen = 0;

__device__ __forceinline__ unsigned short f2bf(float f) {
    unsigned u = __float_as_uint(f);
    u += 0x7fffu + ((u >> 16) & 1u);   // RNE
    return (unsigned short)(u >> 16);
}

// Grid-wide barrier: seq_cst agent-scope atomics provide device-scope
// release/acquire (L2 writeback + invalidate) = the cross-XCD coherence a
// kernel boundary would give. Grid(256 blocks, 16 waves, <=128 VGPR) is
// guaranteed fully co-resident (1 block/CU) -> no deadlock.
__device__ __forceinline__ void grid_sync() {
    __syncthreads();
    if (threadIdx.x == 0) {
        unsigned my = __hip_atomic_load(&g_gen, __ATOMIC_SEQ_CST, __HIP_MEMORY_SCOPE_AGENT);
        unsigned v  = __hip_atomic_fetch_add(&g_cnt, 1u, __ATOMIC_SEQ_CST, __HIP_MEMORY_SCOPE_AGENT);
        if (v == NBLK - 1u) {
            __hip_atomic_store(&g_cnt, 0u, __ATOMIC_SEQ_CST, __HIP_MEMORY_SCOPE_AGENT);
            __hip_atomic_fetch_add(&g_gen, 1u, __ATOMIC_SEQ_CST, __HIP_MEMORY_SCOPE_AGENT);
        } else {
            while (__hip_atomic_load(&g_gen, __ATOMIC_SEQ_CST, __HIP_MEMORY_SCOPE_AGENT) == my)
                __builtin_amdgcn_s_sleep(2);
        }
    }
    __syncthreads();
}

__global__ __launch_bounds__(NTHR, 4) void k_all(
    const float* __restrict__ SL, const float* __restrict__ SR,
    const float* __restrict__ W1, const float* __restrict__ b1,
    const float* __restrict__ W2, const float* __restrict__ b2,
    const int* __restrict__ idxL, const int* __restrict__ idxR,
    unsigned short* __restrict__ Abf, unsigned short* __restrict__ WT,
    float* __restrict__ wd, float* __restrict__ A, float* __restrict__ Bm,
    float* __restrict__ Part, float* __restrict__ out)
{
    __shared__ float4 smem[1024];   // 16 KB: phase0 = two 32x33 transpose tiles; phase2 = Bs
    const int t    = threadIdx.x;
    const int w    = t >> 6;        // wave 0..15
    const int lane = t & 63;
    const int gw   = blockIdx.x * 16 + w;   // global wave id 0..4095

    // ================= phase 0: prep =================
    // (a) gather + bf16-convert 1664 rows (1 row/wave)
    if (gw < NM) {
        long srow; const float* sp;
        if (gw < NL) { srow = idxL[gw];      sp = SL; }
        else         { srow = idxR[gw - NL]; sp = SR; }
        const float* p = sp + srow * FDIM + lane * 8;
        float4 v0 = *(const float4*)(p);
        float4 v1 = *(const float4*)(p + 4);
        ushort8 o;
        o[0]=f2bf(v0.x); o[1]=f2bf(v0.y); o[2]=f2bf(v0.z); o[3]=f2bf(v0.w);
        o[4]=f2bf(v1.x); o[5]=f2bf(v1.y); o[6]=f2bf(v1.z); o[7]=f2bf(v1.w);
        *(ushort8*)(Abf + (long)gw * FDIM + lane * 8) = o;
    }
    // (b) W1 transpose+convert: 512 32x32 tiles, 2 per block (threads 0..511)
    {
        float* tl = (float*)smem;
        const int sel = t >> 8;          // 0..3, tiles use sel<2
        const int t8  = t & 255;
        int ktile = 0, ntile = 0;
        if (sel < 2) {
            const int tt = blockIdx.x * 2 + sel;      // 0..511
            ktile = tt >> 4; ntile = tt & 15;
            const int r  = t8 >> 3;
            const int c4 = (t8 & 7) << 2;
            float4 v = *(const float4*)(&W1[(long)(ktile*32 + r) * FDIM + ntile*32 + c4]);
            float* ta = tl + sel * (32 * 33);
            ta[r*33 + c4+0]=v.x; ta[r*33 + c4+1]=v.y; ta[r*33 + c4+2]=v.z; ta[r*33 + c4+3]=v.w;
        }
        __syncthreads();
        if (sel < 2) {
            const int h  = ktile >> 4;            // W1 half (top/bot)
            const int kb = (ktile & 15) << 5;     // k base within half
            const int nl = t8 >> 3;
            const int k4 = (t8 & 7) << 2;
            const float* ta = tl + sel * (32 * 33);
            ushort4v o;
            o[0]=f2bf(ta[(k4+0)*33 + nl]); o[1]=f2bf(ta[(k4+1)*33 + nl]);
            o[2]=f2bf(ta[(k4+2)*33 + nl]); o[3]=f2bf(ta[(k4+3)*33 + nl]);
            *(ushort4v*)(WT + (long)h*FDIM*FDIM + (long)((ntile<<5) + nl)*FDIM + kb + k4) = o;
        }
    }
    // (c) wd[k] = W2[k][1] - W2[k][0]
    if (blockIdx.x == NBLK - 1 && t < 256) {
        float4 v = *(const float4*)(&W2[t * 4]);
        wd[2*t]   = v.y - v.x;
        wd[2*t+1] = v.w - v.z;
    }
    grid_sync();

    // ================= phase 1: MFMA GEMM =================
    // 1664 wave-tiles of 16(M) x 32(N), K=512, depth-4 register pipeline.
    // mt 0..99 -> A rows (W1 top), mt 100..103 -> Bm rows (W1 bot, +b1).
    // A/B same slot->k mapping (row=lane&15, k=(lane>>4)*8+j); C/D: col=lane&15, row=(lane>>4)*4+r.
    if (gw < 1664) {
        const int mt = gw >> 4, nt = gw & 15;
        const bool isB = mt >= 100;
        const int m0 = (isB ? mt - 100 : mt) << 4;
        const int n0 = nt << 5;
        const int row = lane & 15, g = lane >> 4;
        const short* aP = (const short*)Abf + (long)((isB ? NL : 0) + m0 + row) * FDIM + g * 8;
        const short* bP = (const short*)WT + (isB ? (long)FDIM * FDIM : 0)
                        + (long)(n0 + row) * FDIM + g * 8;
        f32x4 acc0 = {}, acc1 = {};
        short8 a[4], bA[4], bB[4];
        #pragma unroll
        for (int s = 0; s < 4; ++s) {
            a[s]  = *(const short8*)(aP + s * 32);
            bA[s] = *(const short8*)(bP + s * 32);
            bB[s] = *(const short8*)(bP + s * 32 + 16 * FDIM);
        }
        #pragma unroll
        for (int kk = 0; kk < 16; ++kk) {
            const int cur = kk & 3;
            acc0 = __builtin_amdgcn_mfma_f32_16x16x32_bf16(a[cur], bA[cur], acc0, 0, 0, 0);
            acc1 = __builtin_amdgcn_mfma_f32_16x16x32_bf16(a[cur], bB[cur], acc1, 0, 0, 0);
            if (kk < 12) {
                const int ko = (kk + 4) * 32;
                a[cur]  = *(const short8*)(aP + ko);
                bA[cur] = *(const short8*)(bP + ko);
                bB[cur] = *(const short8*)(bP + ko + 16 * FDIM);
            }
        }
        #pragma unroll
        for (int r = 0; r < 4; ++r) {
            const int m  = m0 + g * 4 + r;
            const int na = n0 + row, nb = n0 + 16 + row;
            if (isB) {
                Bm[(long)m * FDIM + na] = acc0[r] + b1[na];
                Bm[(long)m * FDIM + nb] = acc1[r] + b1[nb];
            } else {
                A[(long)m * FDIM + na] = acc0[r];
                A[(long)m * FDIM + nb] = acc1[r];
            }
        }
    }
    grid_sync();

    // ================= phase 2: pairwise relu-dot =================
    // 400 virtual blocks (kq 0..7, lt 0..49), looped x2 over 256 real blocks.
    // Bs = 16KB chunk [16 k4][64 r] float4, XOR r^c layout (stage + read both
    // contiguous-1KB wave accesses). Wave = 2 l-rows, lane = r.
    {
        float4* Bs = smem;
        const float4* Bm4 = (const float4*)Bm;
        const float4* A4  = (const float4*)A;
        const float4* W4  = (const float4*)wd;
        #pragma unroll
        for (int it = 0; it < 2; ++it) {
            const int vb = blockIdx.x + it * NBLK;
            const bool act = vb < 400;
            __syncthreads();   // protect Bs from previous iteration's readers
            if (act) {
                const int kq = vb / 50;
                const int r = t >> 4, c = t & 15;
                Bs[c * 64 + (r ^ c)] = Bm4[r * 128 + kq * 16 + c];
            }
            __syncthreads();
            if (act) {
                const int kq = vb / 50, lt = vb % 50;
                const int lb = lt * 32 + w * 2;
                const float4* A0 = A4 + (long)lb * 128 + kq * 16;
                const float4* A1 = A0 + 128;
                const float4* Wp = W4 + kq * 16;
                float acc0 = 0.f, acc1 = 0.f;
                #pragma unroll
                for (int c = 0; c < 16; ++c) {
                    float4 bv = Bs[c * 64 + (lane ^ c)];
                    float4 wv = Wp[c];
                    float4 a0 = A0[c], a1 = A1[c];
                    acc0 = fmaf(fmaxf(a0.x + bv.x, 0.f), wv.x, acc0);
                    acc0 = fmaf(fmaxf(a0.y + bv.y, 0.f), wv.y, acc0);
                    acc0 = fmaf(fmaxf(a0.z + bv.z, 0.f), wv.z, acc0);
                    acc0 = fmaf(fmaxf(a0.w + bv.w, 0.f), wv.w, acc0);
                    acc1 = fmaf(fmaxf(a1.x + bv.x, 0.f), wv.x, acc1);
                    acc1 = fmaf(fmaxf(a1.y + bv.y, 0.f), wv.y, acc1);
                    acc1 = fmaf(fmaxf(a1.z + bv.z, 0.f), wv.z, acc1);
                    acc1 = fmaf(fmaxf(a1.w + bv.w, 0.f), wv.w, acc1);
                }
                float* P = Part + ((long)kq * NL + lb) * NR + lane;
                P[0]  = acc0;
                P[NR] = acc1;
            }
        }
    }
    grid_sync();

    // ================= phase 3: reduce 8 partials + sigmoid =================
    const int gid = blockIdx.x * NTHR + t;
    if (gid < NL * NR) {
        float s = b2[1] - b2[0];
        #pragma unroll
        for (int q = 0; q < 8; ++q) s += Part[(long)q * NL * NR + gid];
        out[gid] = 1.f / (1.f + expf(-s));
    }
}

extern "C" void kernel_launch(void* const* d_in, const int* in_sizes, int n_in,
                              void* d_out, int out_size, void* d_ws, size_t ws_size,
                              hipStream_t stream) {
    const float* SL  = (const float*)d_in[0];   // [200000,512]
    const float* SR  = (const float*)d_in[1];   // [100000,512]
    const float* W1  = (const float*)d_in[2];   // [1024,512]
    const float* b1  = (const float*)d_in[3];   // [512]
    const float* W2  = (const float*)d_in[4];   // [512,2]
    const float* b2  = (const float*)d_in[5];   // [2]
    const int*   idxL = (const int*)d_in[6];    // [1600]
    const int*   idxR = (const int*)d_in[7];    // [64]
    float* out = (float*)d_out;                 // [1600,64]

    float* A    = (float*)d_ws;                        // [1600,512] f32
    float* Bm   = A + (long)NL * FDIM;                 // [64,512]   f32
    float* wd   = Bm + (long)NR * FDIM;                // [512]      f32
    float* Part = wd + FDIM;                           // [8,1600,64] f32
    unsigned short* Abf = (unsigned short*)(Part + (long)8 * NL * NR);  // [1664,512] bf16
    unsigned short* WT  = Abf + (long)NM * FDIM;                        // [2,512,512] bf16

    k_all<<<NBLK, NTHR, 0, stream>>>(SL, SR, W1, b1, W2, b2, idxL, idxR,
                                     Abf, WT, wd, A, Bm, Part, out);
}

// Round 6
// 82.370 us; speedup vs baseline: 2.1855x; 2.1855x over previous
//
#include <hip/hip_runtime.h>
#include <math.h>

#define FDIM 512
#define NL 1600
#define NR 64
#define NM (NL + NR)   // 1664 gathered rows
#define NBLK 256
#define NTHR 1024

typedef __attribute__((ext_vector_type(8))) short short8;      // 8 bf16 = 4 VGPR (MFMA A/B frag)
typedef __attribute__((ext_vector_type(4))) float f32x4;       // MFMA C/D frag
typedef __attribute__((ext_vector_type(8))) unsigned short ushort8;
typedef __attribute__((ext_vector_type(4))) unsigned short ushort4v;

// Barrier state on SEPARATE cachelines (arriver traffic vs spinner traffic).
// Zero-initialized at module load. g_gen is monotonic (equality-tested only ->
// replay-safe); g_cnt returns to 0 at the end of every barrier.
__device__ unsigned g_cnt[32];   // [0] used
__device__ unsigned g_gen[32];   // [0] used

__device__ __forceinline__ unsigned short f2bf(float f) {
    unsigned u = __float_as_uint(f);
    u += 0x7fffu + ((u >> 16) & 1u);   // RNE
    return (unsigned short)(u >> 16);
}

// Grid barrier, fence-once pattern: the expensive agent-scope fence (L2
// writeback/invalidate, required for cross-XCD visibility) is paid ONCE per
// block per barrier; the spin itself is RELAXED (no cache-maintenance per
// poll). Grid(256 blocks x 16 waves, <=128 VGPR) is fully co-resident
// (1 block/CU) -> no deadlock.
__device__ __forceinline__ void grid_sync() {
    __syncthreads();
    if (threadIdx.x == 0) {
        __threadfence();   // release: my phase writes -> visible device-wide
        unsigned my = __hip_atomic_load(&g_gen[0], __ATOMIC_RELAXED, __HIP_MEMORY_SCOPE_AGENT);
        unsigned v  = __hip_atomic_fetch_add(&g_cnt[0], 1u, __ATOMIC_RELAXED, __HIP_MEMORY_SCOPE_AGENT);
        if (v == NBLK - 1u) {
            __hip_atomic_store(&g_cnt[0], 0u, __ATOMIC_RELAXED, __HIP_MEMORY_SCOPE_AGENT);
            __hip_atomic_store(&g_gen[0], my + 1u, __ATOMIC_RELEASE, __HIP_MEMORY_SCOPE_AGENT);
        } else {
            while (__hip_atomic_load(&g_gen[0], __ATOMIC_RELAXED, __HIP_MEMORY_SCOPE_AGENT) == my)
                __builtin_amdgcn_s_sleep(4);
        }
        __threadfence();   // acquire: make everyone's phase writes visible to me
    }
    __syncthreads();
}

__global__ __launch_bounds__(NTHR, 4) void k_all(
    const float* __restrict__ SL, const float* __restrict__ SR,
    const float* __restrict__ W1, const float* __restrict__ b1,
    const float* __restrict__ W2, const float* __restrict__ b2,
    const int* __restrict__ idxL, const int* __restrict__ idxR,
    unsigned short* __restrict__ Abf, unsigned short* __restrict__ WT,
    float* __restrict__ wd, float* __restrict__ A, float* __restrict__ Bm,
    float* __restrict__ Part, float* __restrict__ out)
{
    __shared__ float4 smem[1024];   // 16 KB: phase0 = two 32x33 transpose tiles; phase2 = Bs
    const int t    = threadIdx.x;
    const int w    = t >> 6;        // wave 0..15
    const int lane = t & 63;
    const int gw   = blockIdx.x * 16 + w;   // global wave id 0..4095

    // ================= phase 0: prep =================
    // (a) gather + bf16-convert 1664 rows (1 row/wave)
    if (gw < NM) {
        long srow; const float* sp;
        if (gw < NL) { srow = idxL[gw];      sp = SL; }
        else         { srow = idxR[gw - NL]; sp = SR; }
        const float* p = sp + srow * FDIM + lane * 8;
        float4 v0 = *(const float4*)(p);
        float4 v1 = *(const float4*)(p + 4);
        ushort8 o;
        o[0]=f2bf(v0.x); o[1]=f2bf(v0.y); o[2]=f2bf(v0.z); o[3]=f2bf(v0.w);
        o[4]=f2bf(v1.x); o[5]=f2bf(v1.y); o[6]=f2bf(v1.z); o[7]=f2bf(v1.w);
        *(ushort8*)(Abf + (long)gw * FDIM + lane * 8) = o;
    }
    // (b) W1 transpose+convert: 512 32x32 tiles, 2 per block (threads 0..511)
    {
        float* tl = (float*)smem;
        const int sel = t >> 8;          // 0..3, tiles use sel<2
        const int t8  = t & 255;
        int ktile = 0, ntile = 0;
        if (sel < 2) {
            const int tt = blockIdx.x * 2 + sel;      // 0..511
            ktile = tt >> 4; ntile = tt & 15;
            const int r  = t8 >> 3;
            const int c4 = (t8 & 7) << 2;
            float4 v = *(const float4*)(&W1[(long)(ktile*32 + r) * FDIM + ntile*32 + c4]);
            float* ta = tl + sel * (32 * 33);
            ta[r*33 + c4+0]=v.x; ta[r*33 + c4+1]=v.y; ta[r*33 + c4+2]=v.z; ta[r*33 + c4+3]=v.w;
        }
        __syncthreads();
        if (sel < 2) {
            const int h  = ktile >> 4;            // W1 half (top/bot)
            const int kb = (ktile & 15) << 5;     // k base within half
            const int nl = t8 >> 3;
            const int k4 = (t8 & 7) << 2;
            const float* ta = tl + sel * (32 * 33);
            ushort4v o;
            o[0]=f2bf(ta[(k4+0)*33 + nl]); o[1]=f2bf(ta[(k4+1)*33 + nl]);
            o[2]=f2bf(ta[(k4+2)*33 + nl]); o[3]=f2bf(ta[(k4+3)*33 + nl]);
            *(ushort4v*)(WT + (long)h*FDIM*FDIM + (long)((ntile<<5) + nl)*FDIM + kb + k4) = o;
        }
    }
    // (c) wd[k] = W2[k][1] - W2[k][0]
    if (blockIdx.x == NBLK - 1 && t < 256) {
        float4 v = *(const float4*)(&W2[t * 4]);
        wd[2*t]   = v.y - v.x;
        wd[2*t+1] = v.w - v.z;
    }
    grid_sync();

    // ================= phase 1: MFMA GEMM =================
    // 1664 wave-tiles of 16(M) x 32(N), K=512, depth-3 register pipeline
    // (27 frag VGPR keeps total well under the 128-VGPR launch-bounds cap).
    // mt 0..99 -> A rows (W1 top), mt 100..103 -> Bm rows (W1 bot, +b1).
    // A/B same slot->k mapping (row=lane&15, k=(lane>>4)*8+j); C/D: col=lane&15, row=(lane>>4)*4+r.
    if (gw < 1664) {
        const int mt = gw >> 4, nt = gw & 15;
        const bool isB = mt >= 100;
        const int m0 = (isB ? mt - 100 : mt) << 4;
        const int n0 = nt << 5;
        const int row = lane & 15, g = lane >> 4;
        const short* aP = (const short*)Abf + (long)((isB ? NL : 0) + m0 + row) * FDIM + g * 8;
        const short* bP = (const short*)WT + (isB ? (long)FDIM * FDIM : 0)
                        + (long)(n0 + row) * FDIM + g * 8;
        f32x4 acc0 = {}, acc1 = {};
        short8 a[3], bA[3], bB[3];
        #pragma unroll
        for (int s = 0; s < 3; ++s) {
            a[s]  = *(const short8*)(aP + s * 32);
            bA[s] = *(const short8*)(bP + s * 32);
            bB[s] = *(const short8*)(bP + s * 32 + 16 * FDIM);
        }
        #pragma unroll
        for (int kk = 0; kk < 16; ++kk) {
            const int cur = kk % 3;                // compile-time after full unroll
            acc0 = __builtin_amdgcn_mfma_f32_16x16x32_bf16(a[cur], bA[cur], acc0, 0, 0, 0);
            acc1 = __builtin_amdgcn_mfma_f32_16x16x32_bf16(a[cur], bB[cur], acc1, 0, 0, 0);
            if (kk < 13) {
                const int ko = (kk + 3) * 32;
                a[cur]  = *(const short8*)(aP + ko);
                bA[cur] = *(const short8*)(bP + ko);
                bB[cur] = *(const short8*)(bP + ko + 16 * FDIM);
            }
        }
        #pragma unroll
        for (int r = 0; r < 4; ++r) {
            const int m  = m0 + g * 4 + r;
            const int na = n0 + row, nb = n0 + 16 + row;
            if (isB) {
                Bm[(long)m * FDIM + na] = acc0[r] + b1[na];
                Bm[(long)m * FDIM + nb] = acc1[r] + b1[nb];
            } else {
                A[(long)m * FDIM + na] = acc0[r];
                A[(long)m * FDIM + nb] = acc1[r];
            }
        }
    }
    grid_sync();

    // ================= phase 2: pairwise relu-dot =================
    // 400 virtual blocks (kq 0..7, lt 0..49), looped x2 over 256 real blocks.
    // Bs = 16KB chunk [16 k4][64 r] float4, XOR r^c layout (stage + read both
    // contiguous-1KB wave accesses). Wave = 2 l-rows, lane = r.
    {
        float4* Bs = smem;
        const float4* Bm4 = (const float4*)Bm;
        const float4* A4  = (const float4*)A;
        const float4* W4  = (const float4*)wd;
        #pragma unroll
        for (int it = 0; it < 2; ++it) {
            const int vb = blockIdx.x + it * NBLK;
            const bool act = vb < 400;
            __syncthreads();   // protect Bs from previous iteration's readers
            if (act) {
                const int kq = vb / 50;
                const int r = t >> 4, c = t & 15;
                Bs[c * 64 + (r ^ c)] = Bm4[r * 128 + kq * 16 + c];
            }
            __syncthreads();
            if (act) {
                const int kq = vb / 50, lt = vb % 50;
                const int lb = lt * 32 + w * 2;
                const float4* A0 = A4 + (long)lb * 128 + kq * 16;
                const float4* A1 = A0 + 128;
                const float4* Wp = W4 + kq * 16;
                float acc0 = 0.f, acc1 = 0.f;
                #pragma unroll
                for (int c = 0; c < 16; ++c) {
                    float4 bv = Bs[c * 64 + (lane ^ c)];
                    float4 wv = Wp[c];
                    float4 a0 = A0[c], a1 = A1[c];
                    acc0 = fmaf(fmaxf(a0.x + bv.x, 0.f), wv.x, acc0);
                    acc0 = fmaf(fmaxf(a0.y + bv.y, 0.f), wv.y, acc0);
                    acc0 = fmaf(fmaxf(a0.z + bv.z, 0.f), wv.z, acc0);
                    acc0 = fmaf(fmaxf(a0.w + bv.w, 0.f), wv.w, acc0);
                    acc1 = fmaf(fmaxf(a1.x + bv.x, 0.f), wv.x, acc1);
                    acc1 = fmaf(fmaxf(a1.y + bv.y, 0.f), wv.y, acc1);
                    acc1 = fmaf(fmaxf(a1.z + bv.z, 0.f), wv.z, acc1);
                    acc1 = fmaf(fmaxf(a1.w + bv.w, 0.f), wv.w, acc1);
                }
                float* P = Part + ((long)kq * NL + lb) * NR + lane;
                P[0]  = acc0;
                P[NR] = acc1;
            }
        }
    }
    grid_sync();

    // ================= phase 3: reduce 8 partials + sigmoid =================
    const int gid = blockIdx.x * NTHR + t;
    if (gid < NL * NR) {
        float s = b2[1] - b2[0];
        #pragma unroll
        for (int q = 0; q < 8; ++q) s += Part[(long)q * NL * NR + gid];
        out[gid] = 1.f / (1.f + expf(-s));
    }
}

extern "C" void kernel_launch(void* const* d_in, const int* in_sizes, int n_in,
                              void* d_out, int out_size, void* d_ws, size_t ws_size,
                              hipStream_t stream) {
    const float* SL  = (const float*)d_in[0];   // [200000,512]
    const float* SR  = (const float*)d_in[1];   // [100000,512]
    const float* W1  = (const float*)d_in[2];   // [1024,512]
    const float* b1  = (const float*)d_in[3];   // [512]
    const float* W2  = (const float*)d_in[4];   // [512,2]
    const float* b2  = (const float*)d_in[5];   // [2]
    const int*   idxL = (const int*)d_in[6];    // [1600]
    const int*   idxR = (const int*)d_in[7];    // [64]
    float* out = (float*)d_out;                 // [1600,64]

    float* A    = (float*)d_ws;                        // [1600,512] f32
    float* Bm   = A + (long)NL * FDIM;                 // [64,512]   f32
    float* wd   = Bm + (long)NR * FDIM;                // [512]      f32
    float* Part = wd + FDIM;                           // [8,1600,64] f32
    unsigned short* Abf = (unsigned short*)(Part + (long)8 * NL * NR);  // [1664,512] bf16
    unsigned short* WT  = Abf + (long)NM * FDIM;                        // [2,512,512] bf16

    k_all<<<NBLK, NTHR, 0, stream>>>(SL, SR, W1, b1, W2, b2, idxL, idxR,
                                     Abf, WT, wd, A, Bm, Part, out);
}